// Round 3
// baseline (1800.811 us; speedup 1.0000x reference)
//
#include <hip/hip_runtime.h>
#include <stdint.h>

// ---------------------------------------------------------------------------
// TopologicalContrastiveLoss: H0 persistence (MST edge weights) of 3 point
// clouds -> 1-Wasserstein between sorted death vectors -> hinge loss.
//
// R3: (a) symmetric GEMM: only 528 upper-triangle 128x128 tiles, mirror tile
// written via LDS transpose (bitwise-identical values). (b) Boruvka scan+merge
// fused into one kernel (last-block ticket pattern; atomicExch read+reset of
// best). (c) norms+split fused into k_prep.
// ---------------------------------------------------------------------------

#define NPTS 4096
#define DIMF 1024
typedef unsigned short u16;
static const unsigned long long KEY_MAX_ULL = ~0ull;

typedef __bf16 bf16x8 __attribute__((ext_vector_type(8)));
typedef float f32x4 __attribute__((ext_vector_type(4)));

#define GLOAD_LDS16(g, l)                                                      \
  __builtin_amdgcn_global_load_lds(                                            \
      (const __attribute__((address_space(1))) void*)(g),                      \
      (__attribute__((address_space(3))) void*)(l), 16, 0, 0)

__device__ __forceinline__ u16 f2bf(float f) {
  unsigned u = __float_as_uint(f);
  u = u + 0x7fffu + ((u >> 16) & 1u);  // RNE
  return (u16)(u >> 16);
}
__device__ __forceinline__ float bf2f(u16 h) {
  return __uint_as_float(((unsigned)h) << 16);
}

// ------------------------------ init ---------------------------------------
__global__ void k_init_global(float* __restrict__ deaths, int* __restrict__ cnt) {
  int i = blockIdx.x * blockDim.x + threadIdx.x;
  if (i < 3 * NPTS) deaths[i] = __int_as_float(0x7f800000);  // +inf pad
  if (i < 4) cnt[i] = 0;  // cnt[0..2]=death counters, cnt[3]=done flag
}

__global__ void k_init_cloud(int* __restrict__ comp,
                             unsigned long long* __restrict__ best,
                             int* __restrict__ done, int* __restrict__ tickets) {
  int i = blockIdx.x * blockDim.x + threadIdx.x;
  if (i < NPTS) { comp[i] = i; best[i] = KEY_MAX_ULL; }
  if (i < 12) tickets[i] = 0;
  if (i == 0) *done = 0;
}

// ------------------------------ prep: norms + hi/lo split -------------------
__global__ __launch_bounds__(256)
void k_prep(const float* __restrict__ x, float* __restrict__ sq,
            u16* __restrict__ hi, u16* __restrict__ lo) {
  const int row = blockIdx.x;
  const int t = threadIdx.x;
  const float4 v = ((const float4*)(x + (size_t)row * DIMF))[t];
  ushort4 h, l;
  h.x = f2bf(v.x); l.x = f2bf(v.x - bf2f(h.x));
  h.y = f2bf(v.y); l.y = f2bf(v.y - bf2f(h.y));
  h.z = f2bf(v.z); l.z = f2bf(v.z - bf2f(h.z));
  h.w = f2bf(v.w); l.w = f2bf(v.w - bf2f(h.w));
  ((ushort4*)(hi + (size_t)row * DIMF))[t] = h;
  ((ushort4*)(lo + (size_t)row * DIMF))[t] = l;
  float s = v.x * v.x + v.y * v.y + v.z * v.z + v.w * v.w;
  for (int off = 32; off > 0; off >>= 1) s += __shfl_xor(s, off, 64);
  __shared__ float ws[4];
  if ((t & 63) == 0) ws[t >> 6] = s;
  __syncthreads();
  if (t == 0) sq[row] = ws[0] + ws[1] + ws[2] + ws[3];
}

// fp32-path norms (fallback)
__global__ __launch_bounds__(256)
void k_norms(const float* __restrict__ x, float* __restrict__ sq) {
  const int row = blockIdx.x;
  const int t = threadIdx.x;
  const float4 v = ((const float4*)(x + (size_t)row * DIMF))[t];
  float s = v.x * v.x + v.y * v.y + v.z * v.z + v.w * v.w;
  for (int off = 32; off > 0; off >>= 1) s += __shfl_xor(s, off, 64);
  __shared__ float ws[4];
  if ((t & 63) == 0) ws[t >> 6] = s;
  __syncthreads();
  if (t == 0) sq[row] = ws[0] + ws[1] + ws[2] + ws[3];
}

// ------------------------------ symmetric MFMA GEMM -------------------------
// 528 upper-triangle tiles; mirror tile via LDS transpose. Virtual K=3072:
// A k-blocks [hi,lo,hi], B k-blocks [hi,hi,lo].
__global__ __launch_bounds__(256)
void k_gemm_sym(const u16* __restrict__ hi, const u16* __restrict__ lo,
                const float* __restrict__ sq, float* __restrict__ d2) {
  __shared__ char smem_raw[16384];
  u16* As = (u16*)smem_raw;                 // 128x32 bf16 (8KB)
  u16* Bs = (u16*)(smem_raw + 8192);        // 128x32 bf16 (8KB)
  float* TR = (float*)smem_raw;             // reused: 64x64 fp32 (16KB)
  const int t = threadIdx.x;
  const int w = t >> 6, l = t & 63;
  const int wm = w >> 1, wn = w & 1;        // 2x2 wave grid, 64x64 each
  const int ml = l & 15, kq = l >> 4;

  // triangular decode: id -> (r, cc) with cc <= r; tile i0=cc*128, j0=r*128
  const int id = blockIdx.x;
  int r = (int)((sqrtf(8.f * (float)id + 1.f) - 1.f) * 0.5f);
  while ((r + 1) * (r + 2) / 2 <= id) ++r;
  while (r * (r + 1) / 2 > id) --r;
  const int cc = id - r * (r + 1) / 2;
  const int i0 = cc * 128, j0 = r * 128;

  const int srow = t >> 2, schk = t & 3;
  char* ldsA0 = smem_raw + t * 16;
  char* ldsB0 = smem_raw + 8192 + t * 16;

  f32x4 acc[4][4];
#pragma unroll
  for (int a = 0; a < 4; ++a)
#pragma unroll
    for (int b = 0; b < 4; ++b) acc[a][b] = (f32x4)0.f;

  for (int k0 = 0; k0 < 3072; k0 += 32) {
    const u16* SA = ((k0 >> 10) == 1) ? lo : hi;
    const u16* SB = ((k0 >> 10) == 2) ? lo : hi;
    const int kc = k0 & 1023;
    __syncthreads();
    {
      const u16* ga0 = SA + (size_t)(i0 + srow) * DIMF + kc + schk * 8;
      const u16* ga1 = SA + (size_t)(i0 + srow + 64) * DIMF + kc + schk * 8;
      const u16* gb0 = SB + (size_t)(j0 + srow) * DIMF + kc + schk * 8;
      const u16* gb1 = SB + (size_t)(j0 + srow + 64) * DIMF + kc + schk * 8;
      GLOAD_LDS16(ga0, ldsA0);
      GLOAD_LDS16(ga1, ldsA0 + 4096);
      GLOAD_LDS16(gb0, ldsB0);
      GLOAD_LDS16(gb1, ldsB0 + 4096);
    }
    asm volatile("s_waitcnt vmcnt(0)" ::: "memory");
    __syncthreads();

    const char* Ab = (const char*)As + (wm * 64 + ml) * 64 + kq * 16;
    const char* Bb = (const char*)Bs + (wn * 64 + ml) * 64 + kq * 16;
    bf16x8 af[4], bf[4];
#pragma unroll
    for (int mt = 0; mt < 4; ++mt) af[mt] = *(const bf16x8*)(Ab + mt * 1024);
#pragma unroll
    for (int nt = 0; nt < 4; ++nt) bf[nt] = *(const bf16x8*)(Bb + nt * 1024);
#pragma unroll
    for (int mt = 0; mt < 4; ++mt)
#pragma unroll
      for (int nt = 0; nt < 4; ++nt)
        acc[mt][nt] = __builtin_amdgcn_mfma_f32_16x16x32_bf16(
            af[mt], bf[nt], acc[mt][nt], 0, 0, 0);
  }

  // epilogue. C/D layout: col=lane&15, row=(lane>>4)*4+reg
  float sr[4][4], sc[4];
#pragma unroll
  for (int mt = 0; mt < 4; ++mt)
#pragma unroll
    for (int rr = 0; rr < 4; ++rr)
      sr[mt][rr] = sq[i0 + wm * 64 + mt * 16 + kq * 4 + rr];
#pragma unroll
  for (int nt = 0; nt < 4; ++nt) sc[nt] = sq[j0 + wn * 64 + nt * 16 + ml];

  __syncthreads();  // all LDS frag reads done before TR reuse

  if (i0 == j0) {  // diagonal tile: direct stores only
#pragma unroll
    for (int mt = 0; mt < 4; ++mt)
#pragma unroll
      for (int nt = 0; nt < 4; ++nt) {
        const int col = j0 + wn * 64 + nt * 16 + ml;
#pragma unroll
        for (int rr = 0; rr < 4; ++rr) {
          const int row = i0 + wm * 64 + mt * 16 + kq * 4 + rr;
          const float v = fmaxf(sr[mt][rr] + sc[nt] - 2.f * acc[mt][nt][rr], 0.f);
          d2[(size_t)row * NPTS + col] = v;
        }
      }
  } else {
    // 4 phases: wave ph writes direct + stages its 64x64 in TR; all mirror.
    for (int ph = 0; ph < 4; ++ph) {
      if (w == ph) {
#pragma unroll
        for (int mt = 0; mt < 4; ++mt)
#pragma unroll
          for (int nt = 0; nt < 4; ++nt) {
            const int lc = nt * 16 + ml;
            const int col = j0 + wn * 64 + lc;
#pragma unroll
            for (int rr = 0; rr < 4; ++rr) {
              const int lr = mt * 16 + kq * 4 + rr;
              const int row = i0 + wm * 64 + lr;
              const float v =
                  fmaxf(sr[mt][rr] + sc[nt] - 2.f * acc[mt][nt][rr], 0.f);
              d2[(size_t)row * NPTS + col] = v;
              TR[lr * 64 + lc] = v;
            }
          }
      }
      __syncthreads();
      {
        const int pwm = ph >> 1, pwn = ph & 1;
        const int c = t >> 2, ch = t & 3;
        float vals[16];
#pragma unroll
        for (int q = 0; q < 16; ++q) vals[q] = TR[(ch * 16 + q) * 64 + c];
        float* dst = d2 + (size_t)(j0 + pwn * 64 + c) * NPTS + i0 + pwm * 64 +
                     ch * 16;
#pragma unroll
        for (int q = 0; q < 4; ++q) {
          float4 o;
          o.x = vals[q * 4 + 0]; o.y = vals[q * 4 + 1];
          o.z = vals[q * 4 + 2]; o.w = vals[q * 4 + 3];
          ((float4*)dst)[q] = o;
        }
      }
      __syncthreads();
    }
  }
}

// ------------------------------ fp32 GEMM fallback --------------------------
#define BM 128
#define BN 128
#define BK 16
__global__ __launch_bounds__(256)
void k_gemm_d2(const float* __restrict__ X, const float* __restrict__ sq,
               float* __restrict__ d2) {
  __shared__ float As[BK][BM];
  __shared__ float Bs[BK][BN];
  const int tid = threadIdx.x;
  const int tx = tid & 15, ty = tid >> 4;
  const int i0 = blockIdx.y * BM, j0 = blockIdx.x * BN;
  float acc[8][8] = {};
  for (int k0 = 0; k0 < DIMF; k0 += BK) {
#pragma unroll
    for (int id = tid; id < 512; id += 256) {
      const int row = id >> 2;
      const int kk = (id & 3) << 2;
      const float4 a = *(const float4*)(X + (size_t)(i0 + row) * DIMF + k0 + kk);
      const float4 b = *(const float4*)(X + (size_t)(j0 + row) * DIMF + k0 + kk);
      As[kk + 0][row] = a.x; As[kk + 1][row] = a.y;
      As[kk + 2][row] = a.z; As[kk + 3][row] = a.w;
      Bs[kk + 0][row] = b.x; Bs[kk + 1][row] = b.y;
      Bs[kk + 2][row] = b.z; Bs[kk + 3][row] = b.w;
    }
    __syncthreads();
#pragma unroll
    for (int kk = 0; kk < BK; ++kk) {
      float a[8], b[8];
#pragma unroll
      for (int m = 0; m < 8; ++m) a[m] = As[kk][ty * 8 + m];
#pragma unroll
      for (int n = 0; n < 8; ++n) b[n] = Bs[kk][tx * 8 + n];
#pragma unroll
      for (int m = 0; m < 8; ++m)
#pragma unroll
        for (int n = 0; n < 8; ++n)
          acc[m][n] = fmaf(a[m], b[n], acc[m][n]);
    }
    __syncthreads();
  }
#pragma unroll
  for (int m = 0; m < 8; ++m) {
    const int i = i0 + ty * 8 + m;
    const float si = sq[i];
    const int j = j0 + tx * 8;
    float4 o0, o1;
    o0.x = fmaxf(si + sq[j + 0] - 2.f * acc[m][0], 0.f);
    o0.y = fmaxf(si + sq[j + 1] - 2.f * acc[m][1], 0.f);
    o0.z = fmaxf(si + sq[j + 2] - 2.f * acc[m][2], 0.f);
    o0.w = fmaxf(si + sq[j + 3] - 2.f * acc[m][3], 0.f);
    o1.x = fmaxf(si + sq[j + 4] - 2.f * acc[m][4], 0.f);
    o1.y = fmaxf(si + sq[j + 5] - 2.f * acc[m][5], 0.f);
    o1.z = fmaxf(si + sq[j + 6] - 2.f * acc[m][6], 0.f);
    o1.w = fmaxf(si + sq[j + 7] - 2.f * acc[m][7], 0.f);
    *(float4*)(d2 + (size_t)i * NPTS + j) = o0;
    *(float4*)(d2 + (size_t)i * NPTS + j + 4) = o1;
  }
}

// ------------------------------ fused Boruvka round -------------------------
// 1024 blocks x 256 threads; block b scans rows 4b..4b+3 (per-component
// atomicMin of 64-bit key). Last block (ticket) then performs the merge:
// hooking + mutual-pair resolution in LDS, death recording, pointer jumping,
// comp writeback, best reset (via atomicExch at read time), done flag.
__global__ __launch_bounds__(256)
void k_round(const float* __restrict__ d2, int* __restrict__ comp,
             unsigned long long* __restrict__ best, float* __restrict__ deaths,
             int* __restrict__ cnt, int* __restrict__ done,
             int* __restrict__ ticket) {
  if (*done) return;
  const int t = threadIdx.x;
  const int blk = blockIdx.x;
  __shared__ unsigned long long red[4];
  __shared__ int flags;
  __shared__ int redi[4];
  __shared__ int par[NPTS];  // 16KB (merge phase)
  __shared__ int hk[NPTS];   // 16KB (merge phase)

  // comp labels for this thread's 16 columns
  int cj[16];
  {
    const int4* cp = (const int4*)comp;
    const int4 a0 = cp[t * 4 + 0], a1 = cp[t * 4 + 1];
    const int4 a2 = cp[t * 4 + 2], a3 = cp[t * 4 + 3];
    cj[0] = a0.x;  cj[1] = a0.y;  cj[2] = a0.z;  cj[3] = a0.w;
    cj[4] = a1.x;  cj[5] = a1.y;  cj[6] = a1.z;  cj[7] = a1.w;
    cj[8] = a2.x;  cj[9] = a2.y;  cj[10] = a2.z; cj[11] = a2.w;
    cj[12] = a3.x; cj[13] = a3.y; cj[14] = a3.z; cj[15] = a3.w;
  }

  for (int rr = 0; rr < 4; ++rr) {
    const int i = blk * 4 + rr;
    const int ci = comp[i];
    const float* row = d2 + (size_t)i * NPTS;
    unsigned long long kmin = KEY_MAX_ULL;
#pragma unroll
    for (int q = 0; q < 4; ++q) {
      const float4 v = ((const float4*)row)[t * 4 + q];
      const float vv[4] = {v.x, v.y, v.z, v.w};
#pragma unroll
      for (int u = 0; u < 4; ++u) {
        const int j = t * 16 + q * 4 + u;
        if (cj[q * 4 + u] != ci) {
          const unsigned long long pair =
              (i < j) ? (((unsigned long long)i << 12) | (unsigned)j)
                      : (((unsigned long long)j << 12) | (unsigned)i);
          const unsigned long long key =
              ((unsigned long long)__float_as_uint(vv[u]) << 24) | pair;
          kmin = (key < kmin) ? key : kmin;
        }
      }
    }
    for (int off = 32; off > 0; off >>= 1) {
      const unsigned long long o = __shfl_xor(kmin, off, 64);
      kmin = (o < kmin) ? o : kmin;
    }
    if ((t & 63) == 0) red[t >> 6] = kmin;
    __syncthreads();
    if (t == 0) {
      unsigned long long k2 = red[0];
      k2 = (red[1] < k2) ? red[1] : k2;
      k2 = (red[2] < k2) ? red[2] : k2;
      k2 = (red[3] < k2) ? red[3] : k2;
      if (k2 != KEY_MAX_ULL) atomicMin(best + ci, k2);
    }
    __syncthreads();
  }

  // ---- last-block ticket ----
  __threadfence();
  if (t == 0) flags = (atomicAdd(ticket, 1) == (int)gridDim.x - 1);
  __syncthreads();
  if (!flags) return;
  __threadfence();

  // ---- merge (one block, 256 threads, 16 items each) ----
  unsigned long long bb[16];
#pragma unroll
  for (int s = 0; s < 16; ++s) {
    const int v = t + s * 256;
    par[v] = comp[v];
    bb[s] = atomicExch(best + v, KEY_MAX_ULL);  // coherent read + reset
  }
  __syncthreads();
#pragma unroll
  for (int s = 0; s < 16; ++s) {
    const int v = t + s * 256;
    const unsigned long long b2 = bb[s];
    int h;
    if (b2 == KEY_MAX_ULL) {
      h = par[v];
    } else {
      const int pair = (int)(b2 & 0xFFFFFF);
      const int a = pair >> 12, c2 = pair & 4095;
      const int ra = par[a], rb = par[c2];
      h = (ra == v) ? rb : ra;  // other component's root
    }
    hk[v] = h;
  }
  __syncthreads();
  bool win[16];
#pragma unroll
  for (int s = 0; s < 16; ++s) {
    const int v = t + s * 256;
    const unsigned long long b2 = bb[s];
    win[s] = false;
    if (b2 != KEY_MAX_ULL) {
      const int so = hk[v];
      const bool mut = (hk[so] == v);
      win[s] = mut && (v < so);
      if (!mut || v < so) {  // each MST edge recorded once
        const float dd = __uint_as_float((unsigned)(b2 >> 24));
        deaths[atomicAdd(cnt, 1)] = sqrtf(fmaxf(dd, 1e-12f));
      }
    }
  }
  __syncthreads();
#pragma unroll
  for (int s = 0; s < 16; ++s)
    if (win[s]) hk[t + s * 256] = t + s * 256;  // mutual winner = new root
  __syncthreads();
  for (int it = 0; it < 12; ++it) {
    int w2[16];
#pragma unroll
    for (int s = 0; s < 16; ++s) w2[s] = hk[hk[t + s * 256]];
    __syncthreads();
#pragma unroll
    for (int s = 0; s < 16; ++s) hk[t + s * 256] = w2[s];
    __syncthreads();
  }
  int nroot = 0;
#pragma unroll
  for (int s = 0; s < 16; ++s) {
    const int v = t + s * 256;
    const int rv = hk[v];
    comp[v] = rv;
    nroot += (rv == v);
  }
  for (int off = 32; off > 0; off >>= 1) nroot += __shfl_xor(nroot, off, 64);
  if ((t & 63) == 0) redi[t >> 6] = nroot;
  __syncthreads();
  if (t == 0) {
    const int tot = redi[0] + redi[1] + redi[2] + redi[3];
    if (tot == 1) *done = 1;
  }
}

// ------------------------------ sort (bitonic, 4096 in LDS) -----------------
__global__ __launch_bounds__(1024)
void k_sort(float* __restrict__ deaths) {
  __shared__ float s[NPTS];
  float* g = deaths + (size_t)blockIdx.x * NPTS;
  const int t = threadIdx.x;
#pragma unroll
  for (int q = 0; q < 4; ++q) s[t + q * 1024] = g[t + q * 1024];
  for (int k = 2; k <= NPTS; k <<= 1) {
    for (int j = k >> 1; j > 0; j >>= 1) {
      __syncthreads();
#pragma unroll
      for (int q = 0; q < 4; ++q) {
        const int i = t + q * 1024;
        const int ixj = i ^ j;
        if (ixj > i) {
          const float a = s[i], b = s[ixj];
          const bool up = ((i & k) == 0);
          if ((a > b) == up) { s[i] = b; s[ixj] = a; }
        }
      }
    }
  }
  __syncthreads();
#pragma unroll
  for (int q = 0; q < 4; ++q) g[t + q * 1024] = s[t + q * 1024];
}

// ------------------------------ final loss ----------------------------------
__global__ __launch_bounds__(1024)
void k_final(const float* __restrict__ deaths, float* __restrict__ out) {
  const float* a = deaths;
  const float* p = deaths + NPTS;
  const float* n = deaths + 2 * NPTS;
  const int t = threadIdx.x;
  float s1 = 0.f, s2 = 0.f;
  for (int i = t; i < NPTS - 1; i += 1024) {
    s1 += fabsf(a[i] - p[i]);
    s2 += fabsf(a[i] - n[i]);
  }
  for (int off = 32; off > 0; off >>= 1) {
    s1 += __shfl_xor(s1, off, 64);
    s2 += __shfl_xor(s2, off, 64);
  }
  __shared__ float r1[16], r2[16];
  if ((t & 63) == 0) { r1[t >> 6] = s1; r2[t >> 6] = s2; }
  __syncthreads();
  if (t == 0) {
    float t1 = 0.f, t2 = 0.f;
    for (int q = 0; q < 16; ++q) { t1 += r1[q]; t2 += r2[q]; }
    out[0] = fmaxf(t1 - t2 + 1.0f, 0.0f);
  }
}

__global__ void k_fail(float* out) { if (threadIdx.x == 0) out[0] = 0.f; }

// ------------------------------ launch --------------------------------------
extern "C" void kernel_launch(void* const* d_in, const int* in_sizes, int n_in,
                              void* d_out, int out_size, void* d_ws, size_t ws_size,
                              hipStream_t stream) {
  const float* xs[3] = {(const float*)d_in[0], (const float*)d_in[1],
                        (const float*)d_in[2]};
  char* ws = (char*)d_ws;
  const size_t d2_bytes = (size_t)NPTS * NPTS * 4;    // 64MB
  const size_t hilo_bytes = (size_t)NPTS * DIMF * 2;  // 8MB each
  const size_t small = NPTS * 4 /*sq*/ + NPTS * 4 /*comp*/ + NPTS * 8 /*best*/ +
                       3 * NPTS * 4 /*deaths*/ + 256 /*cnt+done+tickets*/;
  const size_t need_fp32 = d2_bytes + small;
  const size_t need_mfma = d2_bytes + 2 * hilo_bytes + small;
  if (ws_size < need_fp32) {
    k_fail<<<1, 64, 0, stream>>>((float*)d_out);
    return;
  }
  const bool use_mfma = (ws_size >= need_mfma);
  const size_t tail0 = use_mfma ? (d2_bytes + 2 * hilo_bytes) : d2_bytes;

  float* d2 = (float*)ws;
  u16* hi = (u16*)(ws + d2_bytes);
  u16* lo = (u16*)(ws + d2_bytes + hilo_bytes);
  float* sq = (float*)(ws + tail0);
  int* comp = (int*)(ws + tail0 + NPTS * 4);
  unsigned long long* best = (unsigned long long*)(ws + tail0 + NPTS * 8);
  float* deaths = (float*)(ws + tail0 + NPTS * 16);
  int* cnt = (int*)(ws + tail0 + NPTS * 16 + 3 * NPTS * 4);
  int* done = cnt + 3;
  int* tickets = cnt + 4;  // 12 ints

  k_init_global<<<48, 256, 0, stream>>>(deaths, cnt);
  for (int c = 0; c < 3; ++c) {
    if (use_mfma) {
      k_prep<<<NPTS, 256, 0, stream>>>(xs[c], sq, hi, lo);
    } else {
      k_norms<<<NPTS, 256, 0, stream>>>(xs[c], sq);
    }
    k_init_cloud<<<16, 256, 0, stream>>>(comp, best, done, tickets);
    if (use_mfma) {
      k_gemm_sym<<<528, 256, 0, stream>>>(hi, lo, sq, d2);
    } else {
      k_gemm_d2<<<dim3(NPTS / BN, NPTS / BM), 256, 0, stream>>>(xs[c], sq, d2);
    }
    for (int r = 0; r < 12; ++r) {
      k_round<<<1024, 256, 0, stream>>>(d2, comp, best, deaths + c * NPTS,
                                        cnt + c, done, tickets + r);
    }
  }
  k_sort<<<3, 1024, 0, stream>>>(deaths);
  k_final<<<1, 1024, 0, stream>>>(deaths, (float*)d_out);
}

// Round 4
// 783.442 us; speedup vs baseline: 2.2986x; 2.2986x over previous
//
#include <hip/hip_runtime.h>
#include <stdint.h>

// ---------------------------------------------------------------------------
// TopologicalContrastiveLoss: H0 persistence (MST edge weights) of 3 point
// clouds -> 1-Wasserstein between sorted death vectors -> hinge loss.
//
// R4: revert to R2 skeleton (square GEMM grid, separate scan/merge).
//  (a) pure-fp16 MFMA GEMM, K=1024 (no hi/lo split; error ~0.03 << 0.405).
//  (b) k_scan without LDS comp staging (register labels, ~0 LDS, max TLP).
//  (c) k_merge at 1024 threads, plain loads + plain best-reset (kernel
//      boundary gives coherence; no atomics needed for the read/reset).
// ---------------------------------------------------------------------------

#define NPTS 4096
#define DIMF 1024
typedef unsigned short u16;
typedef _Float16 f16;
static const unsigned long long KEY_MAX_ULL = ~0ull;

typedef f16 f16x8 __attribute__((ext_vector_type(8)));
typedef f16 f16x4v __attribute__((ext_vector_type(4)));
typedef float f32x4 __attribute__((ext_vector_type(4)));

#define GLOAD_LDS16(g, l)                                                      \
  __builtin_amdgcn_global_load_lds(                                            \
      (const __attribute__((address_space(1))) void*)(g),                      \
      (__attribute__((address_space(3))) void*)(l), 16, 0, 0)

// ------------------------------ init ---------------------------------------
__global__ void k_init_global(float* __restrict__ deaths, int* __restrict__ cnt) {
  int i = blockIdx.x * blockDim.x + threadIdx.x;
  if (i < 3 * NPTS) deaths[i] = __int_as_float(0x7f800000);  // +inf pad
  if (i < 4) cnt[i] = 0;  // cnt[0..2]=death counters, cnt[3]=done flag
}

__global__ void k_init_cloud(int* __restrict__ comp,
                             unsigned long long* __restrict__ best,
                             int* __restrict__ done) {
  int i = blockIdx.x * blockDim.x + threadIdx.x;
  if (i < NPTS) { comp[i] = i; best[i] = KEY_MAX_ULL; }
  if (i == 0) *done = 0;
}

// ------------------------------ prep: norms + f16 cast ----------------------
__global__ __launch_bounds__(256)
void k_prep(const float* __restrict__ x, float* __restrict__ sq,
            f16* __restrict__ hi) {
  const int row = blockIdx.x;
  const int t = threadIdx.x;
  const float4 v = ((const float4*)(x + (size_t)row * DIMF))[t];
  f16x4v h;
  h.x = (f16)v.x; h.y = (f16)v.y; h.z = (f16)v.z; h.w = (f16)v.w;
  ((f16x4v*)(hi + (size_t)row * DIMF))[t] = h;
  float s = v.x * v.x + v.y * v.y + v.z * v.z + v.w * v.w;
  for (int off = 32; off > 0; off >>= 1) s += __shfl_xor(s, off, 64);
  __shared__ float ws[4];
  if ((t & 63) == 0) ws[t >> 6] = s;
  __syncthreads();
  if (t == 0) sq[row] = ws[0] + ws[1] + ws[2] + ws[3];
}

// fp32-path norms (fallback)
__global__ __launch_bounds__(256)
void k_norms(const float* __restrict__ x, float* __restrict__ sq) {
  const int row = blockIdx.x;
  const int t = threadIdx.x;
  const float4 v = ((const float4*)(x + (size_t)row * DIMF))[t];
  float s = v.x * v.x + v.y * v.y + v.z * v.z + v.w * v.w;
  for (int off = 32; off > 0; off >>= 1) s += __shfl_xor(s, off, 64);
  __shared__ float ws[4];
  if ((t & 63) == 0) ws[t >> 6] = s;
  __syncthreads();
  if (t == 0) sq[row] = ws[0] + ws[1] + ws[2] + ws[3];
}

// ------------------------------ fp16 MFMA GEMM: d2 --------------------------
// d2[i][j] = max(sq[i]+sq[j]-2*(Hi@Hi^T), 0). K = 1024. 128x128 tile,
// 2x2 wave grid, 16x16x32 f16 MFMA, global_load_lds width=16.
__global__ __launch_bounds__(256)
void k_gemm_f16(const f16* __restrict__ hi, const float* __restrict__ sq,
                float* __restrict__ d2) {
  __shared__ u16 smem[8192];  // As 128x32 f16 (8KB) + Bs 128x32 f16 (8KB)
  u16* As = smem;
  u16* Bs = smem + 4096;
  const int t = threadIdx.x;
  const int w = t >> 6, l = t & 63;
  const int wm = w >> 1, wn = w & 1;           // 2x2 wave grid, 64x64 each
  const int ml = l & 15, kq = l >> 4;          // fragment row / k-quad
  const int i0 = blockIdx.y * 128, j0 = blockIdx.x * 128;

  const int srow = t >> 2, schk = t & 3;
  char* ldsA0 = (char*)As + t * 16;
  char* ldsB0 = (char*)Bs + t * 16;

  f32x4 acc[4][4];
#pragma unroll
  for (int a = 0; a < 4; ++a)
#pragma unroll
    for (int b = 0; b < 4; ++b) acc[a][b] = (f32x4)0.f;

  for (int k0 = 0; k0 < DIMF; k0 += 32) {
    __syncthreads();  // previous iter's compute done before overwrite
    {
      const f16* ga0 = hi + (size_t)(i0 + srow) * DIMF + k0 + schk * 8;
      const f16* ga1 = hi + (size_t)(i0 + srow + 64) * DIMF + k0 + schk * 8;
      const f16* gb0 = hi + (size_t)(j0 + srow) * DIMF + k0 + schk * 8;
      const f16* gb1 = hi + (size_t)(j0 + srow + 64) * DIMF + k0 + schk * 8;
      GLOAD_LDS16(ga0, ldsA0);
      GLOAD_LDS16(ga1, ldsA0 + 4096);
      GLOAD_LDS16(gb0, ldsB0);
      GLOAD_LDS16(gb1, ldsB0 + 4096);
    }
    asm volatile("s_waitcnt vmcnt(0)" ::: "memory");
    __syncthreads();

    const char* Ab = (const char*)As + (wm * 64 + ml) * 64 + kq * 16;
    const char* Bb = (const char*)Bs + (wn * 64 + ml) * 64 + kq * 16;
    f16x8 af[4], bf[4];
#pragma unroll
    for (int mt = 0; mt < 4; ++mt) af[mt] = *(const f16x8*)(Ab + mt * 1024);
#pragma unroll
    for (int nt = 0; nt < 4; ++nt) bf[nt] = *(const f16x8*)(Bb + nt * 1024);
#pragma unroll
    for (int mt = 0; mt < 4; ++mt)
#pragma unroll
      for (int nt = 0; nt < 4; ++nt)
        acc[mt][nt] = __builtin_amdgcn_mfma_f32_16x16x32_f16(
            af[mt], bf[nt], acc[mt][nt], 0, 0, 0);
  }

  // epilogue: C/D layout col=lane&15, row=(lane>>4)*4+reg
  float sr[4][4], sc[4];
#pragma unroll
  for (int mt = 0; mt < 4; ++mt)
#pragma unroll
    for (int r = 0; r < 4; ++r)
      sr[mt][r] = sq[i0 + wm * 64 + mt * 16 + kq * 4 + r];
#pragma unroll
  for (int nt = 0; nt < 4; ++nt) sc[nt] = sq[j0 + wn * 64 + nt * 16 + ml];
#pragma unroll
  for (int mt = 0; mt < 4; ++mt) {
#pragma unroll
    for (int nt = 0; nt < 4; ++nt) {
      const int col = j0 + wn * 64 + nt * 16 + ml;
#pragma unroll
      for (int r = 0; r < 4; ++r) {
        const int row = i0 + wm * 64 + mt * 16 + kq * 4 + r;
        const float v = fmaxf(sr[mt][r] + sc[nt] - 2.f * acc[mt][nt][r], 0.f);
        d2[(size_t)row * NPTS + col] = v;
      }
    }
  }
}

// ------------------------------ fp32 GEMM fallback --------------------------
#define BM 128
#define BN 128
#define BK 16
__global__ __launch_bounds__(256)
void k_gemm_d2(const float* __restrict__ X, const float* __restrict__ sq,
               float* __restrict__ d2) {
  __shared__ float As[BK][BM];
  __shared__ float Bs[BK][BN];
  const int tid = threadIdx.x;
  const int tx = tid & 15, ty = tid >> 4;
  const int i0 = blockIdx.y * BM, j0 = blockIdx.x * BN;
  float acc[8][8] = {};
  for (int k0 = 0; k0 < DIMF; k0 += BK) {
#pragma unroll
    for (int id = tid; id < 512; id += 256) {
      const int row = id >> 2;
      const int kk = (id & 3) << 2;
      const float4 a = *(const float4*)(X + (size_t)(i0 + row) * DIMF + k0 + kk);
      const float4 b = *(const float4*)(X + (size_t)(j0 + row) * DIMF + k0 + kk);
      As[kk + 0][row] = a.x; As[kk + 1][row] = a.y;
      As[kk + 2][row] = a.z; As[kk + 3][row] = a.w;
      Bs[kk + 0][row] = b.x; Bs[kk + 1][row] = b.y;
      Bs[kk + 2][row] = b.z; Bs[kk + 3][row] = b.w;
    }
    __syncthreads();
#pragma unroll
    for (int kk = 0; kk < BK; ++kk) {
      float a[8], b[8];
#pragma unroll
      for (int m = 0; m < 8; ++m) a[m] = As[kk][ty * 8 + m];
#pragma unroll
      for (int n = 0; n < 8; ++n) b[n] = Bs[kk][tx * 8 + n];
#pragma unroll
      for (int m = 0; m < 8; ++m)
#pragma unroll
        for (int n = 0; n < 8; ++n)
          acc[m][n] = fmaf(a[m], b[n], acc[m][n]);
    }
    __syncthreads();
  }
#pragma unroll
  for (int m = 0; m < 8; ++m) {
    const int i = i0 + ty * 8 + m;
    const float si = sq[i];
    const int j = j0 + tx * 8;
    float4 o0, o1;
    o0.x = fmaxf(si + sq[j + 0] - 2.f * acc[m][0], 0.f);
    o0.y = fmaxf(si + sq[j + 1] - 2.f * acc[m][1], 0.f);
    o0.z = fmaxf(si + sq[j + 2] - 2.f * acc[m][2], 0.f);
    o0.w = fmaxf(si + sq[j + 3] - 2.f * acc[m][3], 0.f);
    o1.x = fmaxf(si + sq[j + 4] - 2.f * acc[m][4], 0.f);
    o1.y = fmaxf(si + sq[j + 5] - 2.f * acc[m][5], 0.f);
    o1.z = fmaxf(si + sq[j + 6] - 2.f * acc[m][6], 0.f);
    o1.w = fmaxf(si + sq[j + 7] - 2.f * acc[m][7], 0.f);
    *(float4*)(d2 + (size_t)i * NPTS + j) = o0;
    *(float4*)(d2 + (size_t)i * NPTS + j + 4) = o1;
  }
}

// ------------------------------ Boruvka scan --------------------------------
// One block per vertex i; 16 columns per thread; labels in registers (no LDS
// staging -- comp is L2-hot). Per-component 64-bit atomicMin of
// key = (d2_bits << 24) | canonical_pair24.
__global__ __launch_bounds__(256)
void k_scan(const float* __restrict__ d2, const int* __restrict__ comp,
            unsigned long long* __restrict__ best, const int* __restrict__ done) {
  if (*done) return;
  const int i = blockIdx.x;
  const int t = threadIdx.x;
  __shared__ unsigned long long red[4];

  int cj[16];
  {
    const int4* cp = (const int4*)comp;
    const int4 a0 = cp[t * 4 + 0], a1 = cp[t * 4 + 1];
    const int4 a2 = cp[t * 4 + 2], a3 = cp[t * 4 + 3];
    cj[0] = a0.x;  cj[1] = a0.y;  cj[2] = a0.z;  cj[3] = a0.w;
    cj[4] = a1.x;  cj[5] = a1.y;  cj[6] = a1.z;  cj[7] = a1.w;
    cj[8] = a2.x;  cj[9] = a2.y;  cj[10] = a2.z; cj[11] = a2.w;
    cj[12] = a3.x; cj[13] = a3.y; cj[14] = a3.z; cj[15] = a3.w;
  }
  const int ci = comp[i];
  const float* row = d2 + (size_t)i * NPTS;
  unsigned long long kmin = KEY_MAX_ULL;
#pragma unroll
  for (int q = 0; q < 4; ++q) {
    const float4 v = ((const float4*)row)[t * 4 + q];
    const float vv[4] = {v.x, v.y, v.z, v.w};
#pragma unroll
    for (int u = 0; u < 4; ++u) {
      const int j = t * 16 + q * 4 + u;
      if (cj[q * 4 + u] != ci) {
        const unsigned long long pair =
            (i < j) ? (((unsigned long long)i << 12) | (unsigned)j)
                    : (((unsigned long long)j << 12) | (unsigned)i);
        const unsigned long long key =
            ((unsigned long long)__float_as_uint(vv[u]) << 24) | pair;
        kmin = (key < kmin) ? key : kmin;
      }
    }
  }
  for (int off = 32; off > 0; off >>= 1) {
    const unsigned long long o = __shfl_xor(kmin, off, 64);
    kmin = (o < kmin) ? o : kmin;
  }
  if ((t & 63) == 0) red[t >> 6] = kmin;
  __syncthreads();
  if (t == 0) {
    unsigned long long k2 = red[0];
    k2 = (red[1] < k2) ? red[1] : k2;
    k2 = (red[2] < k2) ? red[2] : k2;
    k2 = (red[3] < k2) ? red[3] : k2;
    if (k2 != KEY_MAX_ULL) atomicMin(best + ci, k2);
  }
}

// ------------------------------ Boruvka merge -------------------------------
// Single workgroup, 1024 threads, 4 items each. Plain loads of best (kernel
// boundary = coherence), plain reset. Hook + mutual resolution + pointer
// jumping in LDS; record deaths; set done when one component remains.
__global__ __launch_bounds__(1024)
void k_merge(unsigned long long* __restrict__ best, int* __restrict__ comp,
             float* __restrict__ deaths, int* __restrict__ cnt,
             int* __restrict__ done) {
  if (*done) return;
  __shared__ int par[NPTS];  // 16KB
  __shared__ int hk[NPTS];   // 16KB
  __shared__ int redi[16];
  const int t = threadIdx.x;
  unsigned long long bb[4];
#pragma unroll
  for (int s = 0; s < 4; ++s) {
    const int v = t + s * 1024;
    par[v] = comp[v];
    bb[s] = best[v];
    best[v] = KEY_MAX_ULL;  // reset for next round
  }
  __syncthreads();
#pragma unroll
  for (int s = 0; s < 4; ++s) {
    const int v = t + s * 1024;
    const unsigned long long b2 = bb[s];
    int h;
    if (b2 == KEY_MAX_ULL) {
      h = par[v];
    } else {
      const int pair = (int)(b2 & 0xFFFFFF);
      const int a = pair >> 12, c2 = pair & 4095;
      const int ra = par[a], rb = par[c2];
      h = (ra == v) ? rb : ra;  // other component's root
    }
    hk[v] = h;
  }
  __syncthreads();
  bool win[4];
#pragma unroll
  for (int s = 0; s < 4; ++s) {
    const int v = t + s * 1024;
    const unsigned long long b2 = bb[s];
    win[s] = false;
    if (b2 != KEY_MAX_ULL) {
      const int so = hk[v];
      const bool mut = (hk[so] == v);
      win[s] = mut && (v < so);
      if (!mut || v < so) {  // each MST edge recorded once
        const float dd = __uint_as_float((unsigned)(b2 >> 24));
        deaths[atomicAdd(cnt, 1)] = sqrtf(fmaxf(dd, 1e-12f));
      }
    }
  }
  __syncthreads();
#pragma unroll
  for (int s = 0; s < 4; ++s)
    if (win[s]) hk[t + s * 1024] = t + s * 1024;  // mutual winner = new root
  __syncthreads();
  for (int it = 0; it < 12; ++it) {
    int w2[4];
#pragma unroll
    for (int s = 0; s < 4; ++s) w2[s] = hk[hk[t + s * 1024]];
    __syncthreads();
#pragma unroll
    for (int s = 0; s < 4; ++s) hk[t + s * 1024] = w2[s];
    __syncthreads();
  }
  int nroot = 0;
#pragma unroll
  for (int s = 0; s < 4; ++s) {
    const int v = t + s * 1024;
    const int rv = hk[v];
    comp[v] = rv;
    nroot += (rv == v);
  }
  for (int off = 32; off > 0; off >>= 1) nroot += __shfl_xor(nroot, off, 64);
  if ((t & 63) == 0) redi[t >> 6] = nroot;
  __syncthreads();
  if (t == 0) {
    int tot = 0;
    for (int q = 0; q < 16; ++q) tot += redi[q];
    if (tot == 1) *done = 1;
  }
}

// ------------------------------ sort (bitonic, 4096 in LDS) -----------------
__global__ __launch_bounds__(1024)
void k_sort(float* __restrict__ deaths) {
  __shared__ float s[NPTS];
  float* g = deaths + (size_t)blockIdx.x * NPTS;
  const int t = threadIdx.x;
#pragma unroll
  for (int q = 0; q < 4; ++q) s[t + q * 1024] = g[t + q * 1024];
  for (int k = 2; k <= NPTS; k <<= 1) {
    for (int j = k >> 1; j > 0; j >>= 1) {
      __syncthreads();
#pragma unroll
      for (int q = 0; q < 4; ++q) {
        const int i = t + q * 1024;
        const int ixj = i ^ j;
        if (ixj > i) {
          const float a = s[i], b = s[ixj];
          const bool up = ((i & k) == 0);
          if ((a > b) == up) { s[i] = b; s[ixj] = a; }
        }
      }
    }
  }
  __syncthreads();
#pragma unroll
  for (int q = 0; q < 4; ++q) g[t + q * 1024] = s[t + q * 1024];
}

// ------------------------------ final loss ----------------------------------
__global__ __launch_bounds__(1024)
void k_final(const float* __restrict__ deaths, float* __restrict__ out) {
  const float* a = deaths;
  const float* p = deaths + NPTS;
  const float* n = deaths + 2 * NPTS;
  const int t = threadIdx.x;
  float s1 = 0.f, s2 = 0.f;
  for (int i = t; i < NPTS - 1; i += 1024) {
    s1 += fabsf(a[i] - p[i]);
    s2 += fabsf(a[i] - n[i]);
  }
  for (int off = 32; off > 0; off >>= 1) {
    s1 += __shfl_xor(s1, off, 64);
    s2 += __shfl_xor(s2, off, 64);
  }
  __shared__ float r1[16], r2[16];
  if ((t & 63) == 0) { r1[t >> 6] = s1; r2[t >> 6] = s2; }
  __syncthreads();
  if (t == 0) {
    float t1 = 0.f, t2 = 0.f;
    for (int q = 0; q < 16; ++q) { t1 += r1[q]; t2 += r2[q]; }
    out[0] = fmaxf(t1 - t2 + 1.0f, 0.0f);
  }
}

__global__ void k_fail(float* out) { if (threadIdx.x == 0) out[0] = 0.f; }

// ------------------------------ launch --------------------------------------
extern "C" void kernel_launch(void* const* d_in, const int* in_sizes, int n_in,
                              void* d_out, int out_size, void* d_ws, size_t ws_size,
                              hipStream_t stream) {
  const float* xs[3] = {(const float*)d_in[0], (const float*)d_in[1],
                        (const float*)d_in[2]};
  char* ws = (char*)d_ws;
  const size_t d2_bytes = (size_t)NPTS * NPTS * 4;   // 64MB
  const size_t hi_bytes = (size_t)NPTS * DIMF * 2;   // 8MB
  const size_t small = NPTS * 4 /*sq*/ + NPTS * 4 /*comp*/ + NPTS * 8 /*best*/ +
                       3 * NPTS * 4 /*deaths*/ + 256;
  const size_t need_fp32 = d2_bytes + small;
  const size_t need_f16 = d2_bytes + hi_bytes + small;
  if (ws_size < need_fp32) {
    k_fail<<<1, 64, 0, stream>>>((float*)d_out);
    return;
  }
  const bool use_f16 = (ws_size >= need_f16);
  const size_t tail0 = use_f16 ? (d2_bytes + hi_bytes) : d2_bytes;

  float* d2 = (float*)ws;
  f16* hi = (f16*)(ws + d2_bytes);
  float* sq = (float*)(ws + tail0);
  int* comp = (int*)(ws + tail0 + NPTS * 4);
  unsigned long long* best = (unsigned long long*)(ws + tail0 + NPTS * 8);
  float* deaths = (float*)(ws + tail0 + NPTS * 16);
  int* cnt = (int*)(ws + tail0 + NPTS * 16 + 3 * NPTS * 4);
  int* done = cnt + 3;

  k_init_global<<<48, 256, 0, stream>>>(deaths, cnt);
  for (int c = 0; c < 3; ++c) {
    if (use_f16) {
      k_prep<<<NPTS, 256, 0, stream>>>(xs[c], sq, hi);
    } else {
      k_norms<<<NPTS, 256, 0, stream>>>(xs[c], sq);
    }
    k_init_cloud<<<16, 256, 0, stream>>>(comp, best, done);
    if (use_f16) {
      k_gemm_f16<<<dim3(NPTS / 128, NPTS / 128), 256, 0, stream>>>(hi, sq, d2);
    } else {
      k_gemm_d2<<<dim3(NPTS / BN, NPTS / BM), 256, 0, stream>>>(xs[c], sq, d2);
    }
    for (int r = 0; r < 12; ++r) {
      k_scan<<<NPTS, 256, 0, stream>>>(d2, comp, best, done);
      k_merge<<<1, 1024, 0, stream>>>(best, comp, deaths + c * NPTS, cnt + c, done);
    }
  }
  k_sort<<<3, 1024, 0, stream>>>(deaths);
  k_final<<<1, 1024, 0, stream>>>(deaths, (float*)d_out);
}